// Round 6
// baseline (934.943 us; speedup 1.0000x reference)
//
#include <hip/hip_runtime.h>
#include <hip/hip_bf16.h>

// Problem dims (fixed by reference)
#define BB   32
#define TT   512
#define CC   1024
#define HH   16
#define DD   64
#define BT   (BB*TT)        // 16384
#define SZROW 1024          // C == H*D == 1024

typedef __bf16 bf16x8 __attribute__((ext_vector_type(8)));
typedef float  f32x4  __attribute__((ext_vector_type(4)));

// async global->LDS, 16B per lane, dest = wave-uniform base + lane*16
#define GLDS16(g, s)                                                        \
    __builtin_amdgcn_global_load_lds(                                       \
        (const __attribute__((address_space(1))) void*)(g),                 \
        (__attribute__((address_space(3))) void*)(s), 16, 0, 0)

// deterministic RNE float->bf16
__device__ __forceinline__ __bf16 tobf(float x) {
    union { float f; uint32_t u; } v; v.f = x;
    uint32_t r = (v.u + 0x7fffu + ((v.u >> 16) & 1u)) >> 16;
    union { unsigned short s; __bf16 b; } o; o.s = (unsigned short)r;
    return o.b;
}
__device__ __forceinline__ uint32_t pk2bf(float a, float b) {
    union { __bf16 h; unsigned short s; } x, y;
    x.h = tobf(a); y.h = tobf(b);
    return ((uint32_t)y.s << 16) | (uint32_t)x.s;
}

// ---------------------------------------------------------------------------
// RoPE cos/sin table: trig[t*16+i] = {cos(t*invf(i)), sin(t*invf(i))}
// ---------------------------------------------------------------------------
__global__ __launch_bounds__(256) void k_trig(float2* __restrict__ trig)
{
    const int idx = blockIdx.x * 256 + threadIdx.x;   // 8192
    const int t = idx >> 4, i = idx & 15;
    const float inv = __expf(-(float)i * 0.5756462732485115f); // ln(10000)/16
    float s, c;
    sincosf((float)t * inv, &s, &c);
    trig[idx] = make_float2(c, s);
}

// ---------------------------------------------------------------------------
// Gather + cast: dst[r][0:1024] = (bf16) src[idx ? idx[r] : r][0:1024]
// ---------------------------------------------------------------------------
__global__ __launch_bounds__(256) void k_cast(const float* __restrict__ src,
                                              const int*   __restrict__ idx,
                                              __bf16*      __restrict__ dst)
{
    const int t   = blockIdx.x * 256 + threadIdx.x;
    const int row = t >> 7;                 // 128 threads per row
    const int c   = (t & 127) << 3;
    const int srow = idx ? idx[row] : row;
    const float* s = src + (size_t)srow * SZROW + c;
    float4 a = *(const float4*)s;
    float4 b = *(const float4*)(s + 4);
    __bf16 o[8] = { tobf(a.x), tobf(a.y), tobf(a.z), tobf(a.w),
                    tobf(b.x), tobf(b.y), tobf(b.z), tobf(b.w) };
    *(uint4*)(dst + (size_t)row * SZROW + c) = *(const uint4*)o;
}

// ---------------------------------------------------------------------------
// Weight transpose + cast for all 4 weights in one dispatch:
// Wt[z][n][k] = (bf16) W_z[k][n].  grid (32,32,4), block 256.
// ---------------------------------------------------------------------------
__global__ __launch_bounds__(256) void k_wt(const float* __restrict__ W0,
                                            const float* __restrict__ W1,
                                            const float* __restrict__ W2,
                                            const float* __restrict__ W3,
                                            __bf16*      __restrict__ Wt)
{
    __shared__ float tile[32][33];
    const int z = blockIdx.z;
    const float* W = (z == 0) ? W0 : (z == 1) ? W1 : (z == 2) ? W2 : W3;
    __bf16* dst = Wt + (size_t)z * SZROW * SZROW;

    const int n0 = blockIdx.x * 32, k0 = blockIdx.y * 32;
    const int t = threadIdx.x;
    const int r = t >> 3, c4 = (t & 7) << 2;
    float4 v = *(const float4*)&W[(size_t)(k0 + r) * SZROW + n0 + c4];
    tile[r][c4 + 0] = v.x; tile[r][c4 + 1] = v.y;
    tile[r][c4 + 2] = v.z; tile[r][c4 + 3] = v.w;
    __syncthreads();
    __bf16 o[4] = { tobf(tile[c4 + 0][r]), tobf(tile[c4 + 1][r]),
                    tobf(tile[c4 + 2][r]), tobf(tile[c4 + 3][r]) };
    *(uint2*)&dst[(size_t)(n0 + r) * SZROW + k0 + c4] = *(const uint2*)o;
}

// ---------------------------------------------------------------------------
// bf16 MFMA GEMM core: acc = A[m0:+128, :] @ Wt[n0:+128, :]^T
// BM=BN=128, BK=32. 256 threads = 4 waves (2x2); each wave 64x64 (4x4 frags).
// Staging: global_load_lds width=16, wave w stages k-group w (one 1024B call
// covers 64 rows x 16B; LDS dest wave-uniform, lane l <-> row l).
// Frag reads: b128, 8 dwords/bank uniform = HW floor, conflict-free.
// ---------------------------------------------------------------------------
__device__ __forceinline__ void gemm_main(const __bf16* __restrict__ A,
                                          const __bf16* __restrict__ Wt,
                                          int m0, int n0,
                                          f32x4 (&acc)[4][4])
{
    __shared__ __bf16 As[4][128][8];
    __shared__ __bf16 Bs[4][128][8];

    const int tid = threadIdx.x;
    const int lane = tid & 63;
    const int wid  = tid >> 6;
    const int wm   = (wid >> 1) << 6;    // 0 or 64
    const int wn   = (wid & 1) << 6;     // 0 or 64

    const int lr = lane & 15;            // frag row/col
    const int lg = lane >> 4;            // frag k-group

    const __bf16* aA0 = A  + (size_t)(m0 + lane)      * 1024 + (wid << 3);
    const __bf16* aA1 = A  + (size_t)(m0 + 64 + lane) * 1024 + (wid << 3);
    const __bf16* aB0 = Wt + (size_t)(n0 + lane)      * 1024 + (wid << 3);
    const __bf16* aB1 = Wt + (size_t)(n0 + 64 + lane) * 1024 + (wid << 3);

    #pragma unroll
    for (int m = 0; m < 4; ++m)
        #pragma unroll
        for (int n = 0; n < 4; ++n) {
            acc[m][n][0] = 0.f; acc[m][n][1] = 0.f;
            acc[m][n][2] = 0.f; acc[m][n][3] = 0.f;
        }

    for (int kt = 0; kt < 1024; kt += 32) {
        __syncthreads();
        GLDS16(aA0 + kt, &As[wid][ 0][0]);
        GLDS16(aA1 + kt, &As[wid][64][0]);
        GLDS16(aB0 + kt, &Bs[wid][ 0][0]);
        GLDS16(aB1 + kt, &Bs[wid][64][0]);
        __syncthreads();   // compiler emits vmcnt(0) drain before barrier

        bf16x8 af[4], bfr[4];
        #pragma unroll
        for (int m = 0; m < 4; ++m)
            af[m] = *(const bf16x8*)&As[lg][wm + (m << 4) + lr][0];
        #pragma unroll
        for (int n = 0; n < 4; ++n)
            bfr[n] = *(const bf16x8*)&Bs[lg][wn + (n << 4) + lr][0];

        #pragma unroll
        for (int m = 0; m < 4; ++m)
            #pragma unroll
            for (int n = 0; n < 4; ++n)
                acc[m][n] = __builtin_amdgcn_mfma_f32_16x16x32_bf16(
                                af[m], bfr[n], acc[m][n], 0, 0, 0);
    }
}

// ---------------------------------------------------------------------------
// QKV projection with fused bias + RoPE + bf16 cast + head-major relayout.
// z=0 -> Qbh[bh][t][d], z=1 -> Kbh[bh][t][d] (both RoPE'd),
// z=2 -> Vtb[bh][d][t] (transposed).
// Lane holds head-cols {lr, lr+16, lr+32, lr+48} -> RoPE pair in-register.
// ---------------------------------------------------------------------------
__global__ __launch_bounds__(256) void k_qkv(const __bf16* __restrict__ Abf,
                                             const __bf16* __restrict__ Wtq,
                                             const __bf16* __restrict__ Wtk,
                                             const __bf16* __restrict__ Wtv,
                                             const float* __restrict__ bq,
                                             const float* __restrict__ bk,
                                             const float* __restrict__ bv,
                                             const float2* __restrict__ trig,
                                             __bf16* __restrict__ Qbh,
                                             __bf16* __restrict__ Kbh,
                                             __bf16* __restrict__ Vtb)
{
    const int z = blockIdx.z;
    const __bf16* W    = (z == 0) ? Wtq : (z == 1) ? Wtk : Wtv;
    const float*  bias = (z == 0) ? bq  : (z == 1) ? bk  : bv;

    const int m0 = blockIdx.y * 128, n0 = blockIdx.x * 128;
    f32x4 acc[4][4];
    gemm_main(Abf, W, m0, n0, acc);

    const int tid = threadIdx.x;
    const int lane = tid & 63, wid = tid >> 6;
    const int wm = (wid >> 1) << 6, wn = (wid & 1) << 6;
    const int lr = lane & 15, lg = lane >> 4;
    const int h = (n0 + wn) >> 6;          // head for this lane's columns

    float bb4[4];
    #pragma unroll
    for (int n = 0; n < 4; ++n) bb4[n] = bias[n0 + wn + (n << 4) + lr];

    if (z < 2) {
        __bf16* dst = (z == 0) ? Qbh : Kbh;
        #pragma unroll
        for (int m = 0; m < 4; ++m) {
            const int rbase = m0 + wm + (m << 4) + (lg << 2);
            const int b  = rbase >> 9;
            const int t0 = rbase & 511;
            const size_t obase = ((size_t)(b * 16 + h)) * 512 * 64;
            #pragma unroll
            for (int i = 0; i < 4; ++i) {
                const int t = t0 + i;
                const float2 cs = trig[(t << 4) + lr];
                const float a0 = acc[m][0][i] + bb4[0];
                const float a1 = acc[m][1][i] + bb4[1];
                const float a2 = acc[m][2][i] + bb4[2];
                const float a3 = acc[m][3][i] + bb4[3];
                const size_t o = obase + (size_t)t * 64;
                dst[o + lr]      = tobf(a0 * cs.x - a1 * cs.y);  // d in [0,16)
                dst[o + lr + 16] = tobf(a1 * cs.x + a0 * cs.y);  // d in [16,32)
                dst[o + lr + 32] = tobf(a2);                     // pass-through
                dst[o + lr + 48] = tobf(a3);
            }
        }
    } else {
        #pragma unroll
        for (int m = 0; m < 4; ++m) {
            const int rbase = m0 + wm + (m << 4) + (lg << 2);
            const int b  = rbase >> 9;
            const int t0 = rbase & 511;
            #pragma unroll
            for (int n = 0; n < 4; ++n) {
                const int d = (n << 4) + lr;
                __bf16 pk[4] = { tobf(acc[m][n][0] + bb4[n]),
                                 tobf(acc[m][n][1] + bb4[n]),
                                 tobf(acc[m][n][2] + bb4[n]),
                                 tobf(acc[m][n][3] + bb4[n]) };
                *(uint2*)&Vtb[((size_t)((b * 16 + h) * 64 + d)) * 512 + t0] =
                    *(const uint2*)pk;
            }
        }
    }
}

// ---------------------------------------------------------------------------
// Output projection: LF[M,1024] = Obf @ Wt3^T + bo (fp32 out)
// ---------------------------------------------------------------------------
__global__ __launch_bounds__(256) void k_proj(const __bf16* __restrict__ Abf,
                                              const __bf16* __restrict__ Wt,
                                              const float* __restrict__ bias,
                                              float* __restrict__ out)
{
    const int m0 = blockIdx.y * 128, n0 = blockIdx.x * 128;
    f32x4 acc[4][4];
    gemm_main(Abf, Wt, m0, n0, acc);

    const int tid = threadIdx.x;
    const int lane = tid & 63, wid = tid >> 6;
    const int wm = (wid >> 1) << 6, wn = (wid & 1) << 6;
    const int lr = lane & 15, lg = lane >> 4;

    #pragma unroll
    for (int n = 0; n < 4; ++n) {
        const int col = n0 + wn + (n << 4) + lr;
        const float bv = bias[col];
        #pragma unroll
        for (int m = 0; m < 4; ++m) {
            const int rbase = m0 + wm + (m << 4) + (lg << 2);
            #pragma unroll
            for (int i = 0; i < 4; ++i)
                out[(size_t)(rbase + i) * SZROW + col] = acc[m][n][i] + bv;
        }
    }
}

// ---------------------------------------------------------------------------
// bf16 MFMA flash attention (causal), fp32 softmax/accum.
// grid (8 qt, 512 bh), block 256 = 4 waves x 16 queries.
// S^T = mfma(K, Q^T): queries in lane&15 -> softmax = 2 shfl_xor.
// K/V^T staged via global_load_lds, slot-XOR swizzle via pre-swizzled source
// (LDS[row][s] holds global chunk s^(row&7); reads XOR the same involution).
// P goes through a per-wave swizzled LDS tile; O += mfma(P, V^T).
// ---------------------------------------------------------------------------
__global__ __launch_bounds__(256) void k_attn(const __bf16* __restrict__ Qbh,
                                              const __bf16* __restrict__ Kbh,
                                              const __bf16* __restrict__ Vtb,
                                              __bf16* __restrict__ Obf)
{
    __shared__ __bf16 Kl[64][64];      // [key][d], slot-swizzled
    __shared__ __bf16 Vl[64][64];      // [d][key], slot-swizzled
    __shared__ __bf16 Pl[4][16][64];   // per-wave [q][key], slot-swizzled

    const int tid = threadIdx.x;
    const int lane = tid & 63, w = tid >> 6;
    const int qt = blockIdx.x, bh = blockIdx.y;
    const int b = bh >> 4, h = bh & 15;
    const int lr = lane & 15, lg = lane >> 4;
    const int sw = lr & 7;

    // Q fragments in registers (B-frag: lane holds Q[q=lr][d = lg*8+j])
    const int qrow = (qt << 6) + (w << 4) + lr;
    const __bf16* qsrc = Qbh + ((size_t)bh * 512 + qrow) * 64 + (lg << 3);
    const bf16x8 qf0 = *(const bf16x8*)(qsrc);
    const bf16x8 qf1 = *(const bf16x8*)(qsrc + 32);

    // staging source (pre-swizzled): wave w covers rows w*16..+16
    const int srow  = (w << 4) + (lane >> 3);
    const int lslot = (lane & 7) ^ (srow & 7);
    const __bf16* ksrc = Kbh + ((size_t)bh * 512 + srow) * 64 + (lslot << 3);
    const __bf16* vsrc = Vtb + ((size_t)bh * 64 + srow) * 512 + (lslot << 3);

    f32x4 oAcc[4];
    #pragma unroll
    for (int n = 0; n < 4; ++n) {
        oAcc[n][0] = 0.f; oAcc[n][1] = 0.f; oAcc[n][2] = 0.f; oAcc[n][3] = 0.f;
    }
    float m_run = -3.0e38f, l_run = 0.0f;

    for (int kt = 0; kt <= qt; ++kt) {
        __syncthreads();
        GLDS16(ksrc + (size_t)((kt << 6) + 0) * 64, &Kl[(w << 4) + 0][0]);
        GLDS16(ksrc + (size_t)((kt << 6) + 8) * 64, &Kl[(w << 4) + 8][0]);
        GLDS16(vsrc + (kt << 6),                    &Vl[(w << 4) + 0][0]);
        GLDS16(vsrc + (kt << 6) + 8 * 512,          &Vl[(w << 4) + 8][0]);
        __syncthreads();

        const bool diag = (kt == qt);
        const int mmax = diag ? w : 3;

        // S^T = K . Q^T  (64 keys x 16 queries per wave)
        f32x4 sT[4];
        #pragma unroll
        for (int m = 0; m < 4; ++m) {
            sT[m][0] = 0.f; sT[m][1] = 0.f; sT[m][2] = 0.f; sT[m][3] = 0.f;
        }
        for (int m = 0; m <= mmax; ++m) {
            const int row = (m << 4) + lr;
            bf16x8 kf0 = *(const bf16x8*)&Kl[row][(lg ^ sw) << 3];
            sT[m] = __builtin_amdgcn_mfma_f32_16x16x32_bf16(kf0, qf0, sT[m], 0, 0, 0);
            bf16x8 kf1 = *(const bf16x8*)&Kl[row][((4 + lg) ^ sw) << 3];
            sT[m] = __builtin_amdgcn_mfma_f32_16x16x32_bf16(kf1, qf1, sT[m], 0, 0, 0);
        }

        // mask + scale + online softmax (q = lr domain)
        float pv[4][4];
        float pmax = -3.0e38f;
        #pragma unroll
        for (int m = 0; m < 4; ++m)
            #pragma unroll
            for (int i = 0; i < 4; ++i) {
                float s = (m <= mmax) ? sT[m][i] * 0.125f : -3.0e38f;
                if (diag && ((m << 4) + (lg << 2) + i > (w << 4) + lr)) s = -3.0e38f;
                pv[m][i] = s;
                pmax = fmaxf(pmax, s);
            }
        pmax = fmaxf(pmax, __shfl_xor(pmax, 16));
        pmax = fmaxf(pmax, __shfl_xor(pmax, 32));
        const float mnew = fmaxf(m_run, pmax);
        const float alpha = __expf(m_run - mnew);
        float psum = 0.0f;
        #pragma unroll
        for (int m = 0; m < 4; ++m)
            #pragma unroll
            for (int i = 0; i < 4; ++i) {
                const float p = __expf(pv[m][i] - mnew);
                pv[m][i] = p;
                psum += p;
            }
        psum += __shfl_xor(psum, 16);
        psum += __shfl_xor(psum, 32);
        l_run = l_run * alpha + psum;
        m_run = mnew;

        // P (bf16) -> Pl[w][q=lr][key] transposed, slot-swizzled
        #pragma unroll
        for (int m = 0; m < 4; ++m)
            #pragma unroll
            for (int ip = 0; ip < 4; ip += 2) {
                const int key = (m << 4) + (lg << 2) + ip;
                const int slot = key >> 3;
                __bf16* dst = &Pl[w][lr][((slot ^ sw) << 3) + (key & 7)];
                *(uint32_t*)dst = pk2bf(pv[m][ip], pv[m][ip + 1]);
            }

        // rescale O by alpha (row domain q = lg*4+i)
        float av[4];
        #pragma unroll
        for (int i = 0; i < 4; ++i) av[i] = __shfl(alpha, (lg << 2) + i);
        #pragma unroll
        for (int n = 0; n < 4; ++n)
            #pragma unroll
            for (int i = 0; i < 4; ++i) oAcc[n][i] *= av[i];

        // O += P . V
        #pragma unroll
        for (int step = 0; step < 2; ++step) {
            const int sl = ((step << 2) + lg) ^ sw;
            bf16x8 paf = *(const bf16x8*)&Pl[w][lr][sl << 3];
            #pragma unroll
            for (int n = 0; n < 4; ++n) {
                bf16x8 vf = *(const bf16x8*)&Vl[(n << 4) + lr][sl << 3];
                oAcc[n] = __builtin_amdgcn_mfma_f32_16x16x32_bf16(paf, vf, oAcc[n], 0, 0, 0);
            }
        }
    }

    // normalize + write bf16 O in [BT][1024] layout
    float linv[4];
    #pragma unroll
    for (int i = 0; i < 4; ++i) linv[i] = 1.0f / __shfl(l_run, (lg << 2) + i);
    #pragma unroll
    for (int n = 0; n < 4; ++n) {
        const int d = (n << 4) + lr;
        #pragma unroll
        for (int i = 0; i < 4; ++i) {
            const int t = (qt << 6) + (w << 4) + (lg << 2) + i;
            Obf[((size_t)(b * 512 + t)) * SZROW + (h << 6) + d] =
                tobf(oAcc[n][i] * linv[i]);
        }
    }
}

// ---------------------------------------------------------------------------
// Epilogue: pos_logits = LF * emb[pos]; neg_logits = rowsum(LF * emb[neg]).
// ---------------------------------------------------------------------------
__global__ __launch_bounds__(256) void k_epi(const float* __restrict__ LF,
                                             const float* __restrict__ emb,
                                             const int*   __restrict__ pos,
                                             const int*   __restrict__ neg,
                                             float* __restrict__ out)
{
    __shared__ float red[4];
    const int r = blockIdx.x;
    const int tid = threadIdx.x;
    const float* lf = LF  + (size_t)r * SZROW;
    const float* pe = emb + (size_t)pos[r] * SZROW;
    const float* ne = emb + (size_t)neg[r] * SZROW;
    float* po = out + (size_t)r * SZROW;

    const int c = tid << 2;
    float4 l4 = *(const float4*)&lf[c];
    float4 p4 = *(const float4*)&pe[c];
    float4 n4 = *(const float4*)&ne[c];
    float4 o4;
    o4.x = l4.x * p4.x; o4.y = l4.y * p4.y; o4.z = l4.z * p4.z; o4.w = l4.w * p4.w;
    *(float4*)&po[c] = o4;

    float nsum = l4.x*n4.x + l4.y*n4.y + l4.z*n4.z + l4.w*n4.w;
    #pragma unroll
    for (int off = 32; off > 0; off >>= 1) nsum += __shfl_down(nsum, off);
    if ((tid & 63) == 0) red[tid >> 6] = nsum;
    __syncthreads();
    if (tid == 0) out[(size_t)BT * SZROW + r] = red[0] + red[1] + red[2] + red[3];
}

// ---------------------------------------------------------------------------
extern "C" void kernel_launch(void* const* d_in, const int* in_sizes, int n_in,
                              void* d_out, int out_size, void* d_ws, size_t ws_size,
                              hipStream_t stream)
{
    const int*   log_seqs = (const int*)  d_in[1];
    const int*   pos_seqs = (const int*)  d_in[2];
    const int*   neg_seqs = (const int*)  d_in[3];
    const float* item_emb = (const float*)d_in[4];
    const float* Wq = (const float*)d_in[5];
    const float* bq = (const float*)d_in[6];
    const float* Wk = (const float*)d_in[7];
    const float* bk = (const float*)d_in[8];
    const float* Wv = (const float*)d_in[9];
    const float* bv = (const float*)d_in[10];
    const float* Wo = (const float*)d_in[11];
    const float* bo = (const float*)d_in[12];

    // Workspace map (peak 168.1 MB):
    //   [0,32M)    Abf        (bf16 gathered activations)   } later overlaid
    //   [32M,64M)  Qbh        (bf16 Q, head-major)          }  by LF (fp32)
    //   [64M,96M)  Kbh
    //   [96M,128M) Vtb        (bf16 V^T)
    //   [128M,160M) Obf       (bf16 attention out, [BT][1024])
    //   [160M,168M) Wt[4]     (bf16 transposed weights)
    //   [168M,+64K) trig
    char* wsb = (char*)d_ws;
    const size_t MB32 = (size_t)32 << 20;
    __bf16* Abf = (__bf16*)(wsb);
    __bf16* Qbh = (__bf16*)(wsb + 1 * MB32);
    __bf16* Kbh = (__bf16*)(wsb + 2 * MB32);
    __bf16* Vtb = (__bf16*)(wsb + 3 * MB32);
    __bf16* Obf = (__bf16*)(wsb + 4 * MB32);
    __bf16* Wt  = (__bf16*)(wsb + 5 * MB32);
    __bf16* Wt0 = Wt;
    __bf16* Wt1 = Wt0 + (size_t)SZROW * SZROW;
    __bf16* Wt2 = Wt1 + (size_t)SZROW * SZROW;
    __bf16* Wt3 = Wt2 + (size_t)SZROW * SZROW;
    float2* trig = (float2*)(wsb + 5 * MB32 + 4 * ((size_t)SZROW * SZROW * 2));
    float*  LF  = (float*)(wsb);            // 64 MB, overlays dead Abf+Qbh
    float* out = (float*)d_out;

    // RoPE table + all 4 weight transposes in one dispatch
    k_trig<<<32, 256, 0, stream>>>(trig);
    k_wt<<<dim3(32, 32, 4), 256, 0, stream>>>(Wq, Wk, Wv, Wo, Wt);

    // gather + cast activations
    k_cast<<<BT * 128 / 256, 256, 0, stream>>>(item_emb, log_seqs, Abf);

    // QKV projections with fused bias+RoPE+cast+relayout
    k_qkv<<<dim3(8, 128, 3), 256, 0, stream>>>(Abf, Wt0, Wt1, Wt2, bq, bk, bv,
                                               trig, Qbh, Kbh, Vtb);

    // MFMA flash attention -> Obf (bf16, [BT][1024])
    k_attn<<<dim3(8, 512), 256, 0, stream>>>(Qbh, Kbh, Vtb, Obf);

    // output projection (LF overlays Abf/Qbh, both dead now)
    k_proj<<<dim3(8, 128, 1), 256, 0, stream>>>(Obf, Wt3, bo, LF);

    k_epi<<<BT, 256, 0, stream>>>(LF, item_emb, pos_seqs, neg_seqs, out);
}

// Round 7
// 914.382 us; speedup vs baseline: 1.0225x; 1.0225x over previous
//
#include <hip/hip_runtime.h>
#include <hip/hip_bf16.h>

// Problem dims (fixed by reference)
#define BB   32
#define TT   512
#define CC   1024
#define HH   16
#define DD   64
#define BT   (BB*TT)        // 16384
#define SZROW 1024          // C == H*D == 1024

typedef __bf16 bf16x8 __attribute__((ext_vector_type(8)));
typedef float  f32x4  __attribute__((ext_vector_type(4)));

// async global->LDS, 16B per lane, dest = wave-uniform base + lane*16
#define GLDS16(g, s)                                                        \
    __builtin_amdgcn_global_load_lds(                                       \
        (const __attribute__((address_space(1))) void*)(g),                 \
        (__attribute__((address_space(3))) void*)(s), 16, 0, 0)

// deterministic RNE float->bf16
__device__ __forceinline__ __bf16 tobf(float x) {
    union { float f; uint32_t u; } v; v.f = x;
    uint32_t r = (v.u + 0x7fffu + ((v.u >> 16) & 1u)) >> 16;
    union { unsigned short s; __bf16 b; } o; o.s = (unsigned short)r;
    return o.b;
}
__device__ __forceinline__ uint32_t pk2bf(float a, float b) {
    union { __bf16 h; unsigned short s; } x, y;
    x.h = tobf(a); y.h = tobf(b);
    return ((uint32_t)y.s << 16) | (uint32_t)x.s;
}

// ---------------------------------------------------------------------------
// RoPE cos/sin table: trig[t*16+i] = {cos(t*invf(i)), sin(t*invf(i))}
// ---------------------------------------------------------------------------
__global__ __launch_bounds__(256) void k_trig(float2* __restrict__ trig)
{
    const int idx = blockIdx.x * 256 + threadIdx.x;   // 8192
    const int t = idx >> 4, i = idx & 15;
    const float inv = __expf(-(float)i * 0.5756462732485115f); // ln(10000)/16
    float s, c;
    sincosf((float)t * inv, &s, &c);
    trig[idx] = make_float2(c, s);
}

// zero-init neg_logits region of d_out (poisoned 0xAA each iteration)
__global__ __launch_bounds__(256) void k_zero(float* __restrict__ p)
{
    p[blockIdx.x * 256 + threadIdx.x] = 0.0f;
}

// ---------------------------------------------------------------------------
// Gather + cast: dst[r][0:1024] = (bf16) src[idx[r]][0:1024]
// ---------------------------------------------------------------------------
__global__ __launch_bounds__(256) void k_cast(const float* __restrict__ src,
                                              const int*   __restrict__ idx,
                                              __bf16*      __restrict__ dst)
{
    const int t   = blockIdx.x * 256 + threadIdx.x;
    const int row = t >> 7;                 // 128 threads per row
    const int c   = (t & 127) << 3;
    const int srow = idx[row];
    const float* s = src + (size_t)srow * SZROW + c;
    float4 a = *(const float4*)s;
    float4 b = *(const float4*)(s + 4);
    __bf16 o[8] = { tobf(a.x), tobf(a.y), tobf(a.z), tobf(a.w),
                    tobf(b.x), tobf(b.y), tobf(b.z), tobf(b.w) };
    *(uint4*)(dst + (size_t)row * SZROW + c) = *(const uint4*)o;
}

// ---------------------------------------------------------------------------
// Weight transpose + cast for all 4 weights in one dispatch:
// Wt[z][n][k] = (bf16) W_z[k][n].  grid (32,32,4), block 256.
// ---------------------------------------------------------------------------
__global__ __launch_bounds__(256) void k_wt(const float* __restrict__ W0,
                                            const float* __restrict__ W1,
                                            const float* __restrict__ W2,
                                            const float* __restrict__ W3,
                                            __bf16*      __restrict__ Wt)
{
    __shared__ float tile[32][33];
    const int z = blockIdx.z;
    const float* W = (z == 0) ? W0 : (z == 1) ? W1 : (z == 2) ? W2 : W3;
    __bf16* dst = Wt + (size_t)z * SZROW * SZROW;

    const int n0 = blockIdx.x * 32, k0 = blockIdx.y * 32;
    const int t = threadIdx.x;
    const int r = t >> 3, c4 = (t & 7) << 2;
    float4 v = *(const float4*)&W[(size_t)(k0 + r) * SZROW + n0 + c4];
    tile[r][c4 + 0] = v.x; tile[r][c4 + 1] = v.y;
    tile[r][c4 + 2] = v.z; tile[r][c4 + 3] = v.w;
    __syncthreads();
    __bf16 o[4] = { tobf(tile[c4 + 0][r]), tobf(tile[c4 + 1][r]),
                    tobf(tile[c4 + 2][r]), tobf(tile[c4 + 3][r]) };
    *(uint2*)&dst[(size_t)(n0 + r) * SZROW + k0 + c4] = *(const uint2*)o;
}

// ---------------------------------------------------------------------------
// bf16 MFMA GEMM core: acc = A[m0:+128, :] @ Wt[n0:+128, :]^T
// BM=BN=128, BK=32. 256 threads = 4 waves (2x2); each wave 64x64 (4x4 frags).
// Staging: global_load_lds width=16, wave w stages k-group w.
// ---------------------------------------------------------------------------
__device__ __forceinline__ void gemm_main(const __bf16* __restrict__ A,
                                          const __bf16* __restrict__ Wt,
                                          int m0, int n0,
                                          f32x4 (&acc)[4][4])
{
    __shared__ __bf16 As[4][128][8];
    __shared__ __bf16 Bs[4][128][8];

    const int tid = threadIdx.x;
    const int lane = tid & 63;
    const int wid  = tid >> 6;
    const int wm   = (wid >> 1) << 6;    // 0 or 64
    const int wn   = (wid & 1) << 6;     // 0 or 64

    const int lr = lane & 15;            // frag row/col
    const int lg = lane >> 4;            // frag k-group

    const __bf16* aA0 = A  + (size_t)(m0 + lane)      * 1024 + (wid << 3);
    const __bf16* aA1 = A  + (size_t)(m0 + 64 + lane) * 1024 + (wid << 3);
    const __bf16* aB0 = Wt + (size_t)(n0 + lane)      * 1024 + (wid << 3);
    const __bf16* aB1 = Wt + (size_t)(n0 + 64 + lane) * 1024 + (wid << 3);

    #pragma unroll
    for (int m = 0; m < 4; ++m)
        #pragma unroll
        for (int n = 0; n < 4; ++n) {
            acc[m][n][0] = 0.f; acc[m][n][1] = 0.f;
            acc[m][n][2] = 0.f; acc[m][n][3] = 0.f;
        }

    for (int kt = 0; kt < 1024; kt += 32) {
        __syncthreads();
        GLDS16(aA0 + kt, &As[wid][ 0][0]);
        GLDS16(aA1 + kt, &As[wid][64][0]);
        GLDS16(aB0 + kt, &Bs[wid][ 0][0]);
        GLDS16(aB1 + kt, &Bs[wid][64][0]);
        __syncthreads();   // compiler emits vmcnt(0) drain before barrier

        bf16x8 af[4], bfr[4];
        #pragma unroll
        for (int m = 0; m < 4; ++m)
            af[m] = *(const bf16x8*)&As[lg][wm + (m << 4) + lr][0];
        #pragma unroll
        for (int n = 0; n < 4; ++n)
            bfr[n] = *(const bf16x8*)&Bs[lg][wn + (n << 4) + lr][0];

        #pragma unroll
        for (int m = 0; m < 4; ++m)
            #pragma unroll
            for (int n = 0; n < 4; ++n)
                acc[m][n] = __builtin_amdgcn_mfma_f32_16x16x32_bf16(
                                af[m], bfr[n], acc[m][n], 0, 0, 0);
    }
}

// ---------------------------------------------------------------------------
// QKV projection with fused bias + RoPE + bf16 cast + head-major relayout.
// z=0 -> Qbh[bh][t][d], z=1 -> Kbh[bh][t][d] (both RoPE'd),
// z=2 -> Vtb[bh][d][t] (transposed).
// XCD swizzle: the 8 n-blocks sharing an A-panel keep the same (lin&7).
// ---------------------------------------------------------------------------
__global__ __launch_bounds__(256) void k_qkv(const __bf16* __restrict__ Abf,
                                             const __bf16* __restrict__ Wtq,
                                             const __bf16* __restrict__ Wtk,
                                             const __bf16* __restrict__ Wtv,
                                             const float* __restrict__ bq,
                                             const float* __restrict__ bk,
                                             const float* __restrict__ bv,
                                             const float2* __restrict__ trig,
                                             __bf16* __restrict__ Qbh,
                                             __bf16* __restrict__ Kbh,
                                             __bf16* __restrict__ Vtb)
{
    const int z = blockIdx.z;
    const __bf16* W    = (z == 0) ? Wtq : (z == 1) ? Wtk : Wtv;
    const float*  bias = (z == 0) ? bq  : (z == 1) ? bk  : bv;

    // XCD-aware bijective remap: lin = (m&7) + 8*(m>>3) + 128*n
    const int lin = blockIdx.x + (blockIdx.y << 3);       // 0..1023
    const int m_blk = (lin & 7) + (((lin >> 3) & 15) << 3);
    const int n_blk = lin >> 7;
    const int m0 = m_blk * 128, n0 = n_blk * 128;

    f32x4 acc[4][4];
    gemm_main(Abf, W, m0, n0, acc);

    const int tid = threadIdx.x;
    const int lane = tid & 63, wid = tid >> 6;
    const int wm = (wid >> 1) << 6, wn = (wid & 1) << 6;
    const int lr = lane & 15, lg = lane >> 4;
    const int h = (n0 + wn) >> 6;          // head for this lane's columns

    float bb4[4];
    #pragma unroll
    for (int n = 0; n < 4; ++n) bb4[n] = bias[n0 + wn + (n << 4) + lr];

    if (z < 2) {
        __bf16* dst = (z == 0) ? Qbh : Kbh;
        #pragma unroll
        for (int m = 0; m < 4; ++m) {
            const int rbase = m0 + wm + (m << 4) + (lg << 2);
            const int b  = rbase >> 9;
            const int t0 = rbase & 511;
            const size_t obase = ((size_t)(b * 16 + h)) * 512 * 64;
            #pragma unroll
            for (int i = 0; i < 4; ++i) {
                const int t = t0 + i;
                const float2 cs = trig[(t << 4) + lr];
                const float a0 = acc[m][0][i] + bb4[0];
                const float a1 = acc[m][1][i] + bb4[1];
                const float a2 = acc[m][2][i] + bb4[2];
                const float a3 = acc[m][3][i] + bb4[3];
                const size_t o = obase + (size_t)t * 64;
                dst[o + lr]      = tobf(a0 * cs.x - a1 * cs.y);  // d in [0,16)
                dst[o + lr + 16] = tobf(a1 * cs.x + a0 * cs.y);  // d in [16,32)
                dst[o + lr + 32] = tobf(a2);                     // pass-through
                dst[o + lr + 48] = tobf(a3);
            }
        }
    } else {
        #pragma unroll
        for (int m = 0; m < 4; ++m) {
            const int rbase = m0 + wm + (m << 4) + (lg << 2);
            const int b  = rbase >> 9;
            const int t0 = rbase & 511;
            #pragma unroll
            for (int n = 0; n < 4; ++n) {
                const int d = (n << 4) + lr;
                __bf16 pk[4] = { tobf(acc[m][n][0] + bb4[n]),
                                 tobf(acc[m][n][1] + bb4[n]),
                                 tobf(acc[m][n][2] + bb4[n]),
                                 tobf(acc[m][n][3] + bb4[n]) };
                *(uint2*)&Vtb[((size_t)((b * 16 + h) * 64 + d)) * 512 + t0] =
                    *(const uint2*)pk;
            }
        }
    }
}

// ---------------------------------------------------------------------------
// Output projection fused with logits epilogue:
//   LF = Obf @ Wt3^T + bo (in regs);
//   pos_logits[r][c] = LF[r][c] * emb[pos[r]][c]   (written directly)
//   neg_logits[r]   += sum_c LF[r][c]*emb[neg[r]][c] (shfl-reduce + atomicAdd)
// ---------------------------------------------------------------------------
__global__ __launch_bounds__(256) void k_projepi(const __bf16* __restrict__ Obf,
                                                 const __bf16* __restrict__ Wt,
                                                 const float* __restrict__ bias,
                                                 const float* __restrict__ emb,
                                                 const int*   __restrict__ pos,
                                                 const int*   __restrict__ neg,
                                                 float* __restrict__ out)
{
    const int lin = blockIdx.x + (blockIdx.y << 3);       // 0..1023
    const int m_blk = (lin & 7) + (((lin >> 3) & 15) << 3);
    const int n_blk = lin >> 7;
    const int m0 = m_blk * 128, n0 = n_blk * 128;

    f32x4 acc[4][4];
    gemm_main(Obf, Wt, m0, n0, acc);

    const int tid = threadIdx.x;
    const int lane = tid & 63, wid = tid >> 6;
    const int wm = (wid >> 1) << 6, wn = (wid & 1) << 6;
    const int lr = lane & 15, lg = lane >> 4;

    float bb4[4];
    #pragma unroll
    for (int n = 0; n < 4; ++n) bb4[n] = bias[n0 + wn + (n << 4) + lr];

    float* negout = out + (size_t)BT * SZROW;

    #pragma unroll
    for (int m = 0; m < 4; ++m) {
        const int rbase = m0 + wm + (m << 4) + (lg << 2);
        #pragma unroll
        for (int i = 0; i < 4; ++i) {
            const int row = rbase + i;
            const size_t pbase = (size_t)pos[row] * SZROW;
            const size_t nbase = (size_t)neg[row] * SZROW;
            float nsum = 0.0f;
            #pragma unroll
            for (int n = 0; n < 4; ++n) {
                const int col = n0 + wn + (n << 4) + lr;
                const float lf = acc[m][n][i] + bb4[n];
                out[(size_t)row * SZROW + col] = lf * emb[pbase + col];
                nsum = fmaf(lf, emb[nbase + col], nsum);
            }
            nsum += __shfl_xor(nsum, 1);
            nsum += __shfl_xor(nsum, 2);
            nsum += __shfl_xor(nsum, 4);
            nsum += __shfl_xor(nsum, 8);
            if (lr == 0) atomicAdd(&negout[row], nsum);
        }
    }
}

// ---------------------------------------------------------------------------
// bf16 MFMA flash attention (causal), fp32 softmax/accum.
// grid (8 qt, 512 bh), block 256 = 4 waves x 16 queries.
// XCD swizzle: the 8 qt-blocks sharing one (b,h)'s K/V keep the same (lin&7).
// ---------------------------------------------------------------------------
__global__ __launch_bounds__(256) void k_attn(const __bf16* __restrict__ Qbh,
                                              const __bf16* __restrict__ Kbh,
                                              const __bf16* __restrict__ Vtb,
                                              __bf16* __restrict__ Obf)
{
    __shared__ __bf16 Kl[64][64];      // [key][d], slot-swizzled
    __shared__ __bf16 Vl[64][64];      // [d][key], slot-swizzled
    __shared__ __bf16 Pl[4][16][64];   // per-wave [q][key], slot-swizzled

    const int tid = threadIdx.x;
    const int lane = tid & 63, w = tid >> 6;
    // XCD-aware bijective remap: lin = (bh&7) + 8*qt + 64*(bh>>3)
    const int lin = blockIdx.x + (blockIdx.y << 3);       // 0..4095
    const int qt = (lin >> 3) & 7;
    const int bh = (lin & 7) + ((lin >> 6) << 3);
    const int b = bh >> 4, h = bh & 15;
    const int lr = lane & 15, lg = lane >> 4;
    const int sw = lr & 7;

    // Q fragments in registers (B-frag: lane holds Q[q=lr][d = lg*8+j])
    const int qrow = (qt << 6) + (w << 4) + lr;
    const __bf16* qsrc = Qbh + ((size_t)bh * 512 + qrow) * 64 + (lg << 3);
    const bf16x8 qf0 = *(const bf16x8*)(qsrc);
    const bf16x8 qf1 = *(const bf16x8*)(qsrc + 32);

    // staging source (pre-swizzled): wave w covers rows w*16..+16
    const int srow  = (w << 4) + (lane >> 3);
    const int lslot = (lane & 7) ^ (srow & 7);
    const __bf16* ksrc = Kbh + ((size_t)bh * 512 + srow) * 64 + (lslot << 3);
    const __bf16* vsrc = Vtb + ((size_t)bh * 64 + srow) * 512 + (lslot << 3);

    f32x4 oAcc[4];
    #pragma unroll
    for (int n = 0; n < 4; ++n) {
        oAcc[n][0] = 0.f; oAcc[n][1] = 0.f; oAcc[n][2] = 0.f; oAcc[n][3] = 0.f;
    }
    float m_run = -3.0e38f, l_run = 0.0f;

    for (int kt = 0; kt <= qt; ++kt) {
        __syncthreads();
        GLDS16(ksrc + (size_t)((kt << 6) + 0) * 64, &Kl[(w << 4) + 0][0]);
        GLDS16(ksrc + (size_t)((kt << 6) + 8) * 64, &Kl[(w << 4) + 8][0]);
        GLDS16(vsrc + (kt << 6),                    &Vl[(w << 4) + 0][0]);
        GLDS16(vsrc + (kt << 6) + 8 * 512,          &Vl[(w << 4) + 8][0]);
        __syncthreads();

        const bool diag = (kt == qt);
        const int mmax = diag ? w : 3;

        // S^T = K . Q^T  (64 keys x 16 queries per wave)
        f32x4 sT[4];
        #pragma unroll
        for (int m = 0; m < 4; ++m) {
            sT[m][0] = 0.f; sT[m][1] = 0.f; sT[m][2] = 0.f; sT[m][3] = 0.f;
        }
        for (int m = 0; m <= mmax; ++m) {
            const int row = (m << 4) + lr;
            bf16x8 kf0 = *(const bf16x8*)&Kl[row][(lg ^ sw) << 3];
            sT[m] = __builtin_amdgcn_mfma_f32_16x16x32_bf16(kf0, qf0, sT[m], 0, 0, 0);
            bf16x8 kf1 = *(const bf16x8*)&Kl[row][((4 + lg) ^ sw) << 3];
            sT[m] = __builtin_amdgcn_mfma_f32_16x16x32_bf16(kf1, qf1, sT[m], 0, 0, 0);
        }

        // mask + scale + online softmax (q = lr domain)
        float pv[4][4];
        float pmax = -3.0e38f;
        #pragma unroll
        for (int m = 0; m < 4; ++m)
            #pragma unroll
            for (int i = 0; i < 4; ++i) {
                float s = (m <= mmax) ? sT[m][i] * 0.125f : -3.0e38f;
                if (diag && ((m << 4) + (lg << 2) + i > (w << 4) + lr)) s = -3.0e38f;
                pv[m][i] = s;
                pmax = fmaxf(pmax, s);
            }
        pmax = fmaxf(pmax, __shfl_xor(pmax, 16));
        pmax = fmaxf(pmax, __shfl_xor(pmax, 32));
        const float mnew = fmaxf(m_run, pmax);
        const float alpha = __expf(m_run - mnew);
        float psum = 0.0f;
        #pragma unroll
        for (int m = 0; m < 4; ++m)
            #pragma unroll
            for (int i = 0; i < 4; ++i) {
                const float p = __expf(pv[m][i] - mnew);
                pv[m][i] = p;
                psum += p;
            }
        psum += __shfl_xor(psum, 16);
        psum += __shfl_xor(psum, 32);
        l_run = l_run * alpha + psum;
        m_run = mnew;

        // P (bf16) -> Pl[w][q=lr][key] transposed, slot-swizzled
        #pragma unroll
        for (int m = 0; m < 4; ++m)
            #pragma unroll
            for (int ip = 0; ip < 4; ip += 2) {
                const int key = (m << 4) + (lg << 2) + ip;
                const int slot = key >> 3;
                __bf16* dst = &Pl[w][lr][((slot ^ sw) << 3) + (key & 7)];
                *(uint32_t*)dst = pk2bf(pv[m][ip], pv[m][ip + 1]);
            }

        // rescale O by alpha (row domain q = lg*4+i)
        float av[4];
        #pragma unroll
        for (int i = 0; i < 4; ++i) av[i] = __shfl(alpha, (lg << 2) + i);
        #pragma unroll
        for (int n = 0; n < 4; ++n)
            #pragma unroll
            for (int i = 0; i < 4; ++i) oAcc[n][i] *= av[i];

        // O += P . V  (skip all-masked key slots 32..63 on diag for waves 0,1)
        const int nstep = (diag && w < 2) ? 1 : 2;
        for (int step = 0; step < nstep; ++step) {
            const int sl = ((step << 2) + lg) ^ sw;
            bf16x8 paf = *(const bf16x8*)&Pl[w][lr][sl << 3];
            #pragma unroll
            for (int n = 0; n < 4; ++n) {
                bf16x8 vf = *(const bf16x8*)&Vl[(n << 4) + lr][sl << 3];
                oAcc[n] = __builtin_amdgcn_mfma_f32_16x16x32_bf16(paf, vf, oAcc[n], 0, 0, 0);
            }
        }
    }

    // normalize + write bf16 O in [BT][1024] layout
    float linv[4];
    #pragma unroll
    for (int i = 0; i < 4; ++i) linv[i] = 1.0f / __shfl(l_run, (lg << 2) + i);
    #pragma unroll
    for (int n = 0; n < 4; ++n) {
        const int d = (n << 4) + lr;
        #pragma unroll
        for (int i = 0; i < 4; ++i) {
            const int t = (qt << 6) + (w << 4) + (lg << 2) + i;
            Obf[((size_t)(b * 512 + t)) * SZROW + (h << 6) + d] =
                tobf(oAcc[n][i] * linv[i]);
        }
    }
}

// ---------------------------------------------------------------------------
extern "C" void kernel_launch(void* const* d_in, const int* in_sizes, int n_in,
                              void* d_out, int out_size, void* d_ws, size_t ws_size,
                              hipStream_t stream)
{
    const int*   log_seqs = (const int*)  d_in[1];
    const int*   pos_seqs = (const int*)  d_in[2];
    const int*   neg_seqs = (const int*)  d_in[3];
    const float* item_emb = (const float*)d_in[4];
    const float* Wq = (const float*)d_in[5];
    const float* bq = (const float*)d_in[6];
    const float* Wk = (const float*)d_in[7];
    const float* bk = (const float*)d_in[8];
    const float* Wv = (const float*)d_in[9];
    const float* bv = (const float*)d_in[10];
    const float* Wo = (const float*)d_in[11];
    const float* bo = (const float*)d_in[12];

    // Workspace map (peak 168.1 MB):
    //   [0,32M)     Abf   (bf16 gathered activations)
    //   [32M,64M)   Qbh   (bf16 Q, head-major)
    //   [64M,96M)   Kbh
    //   [96M,128M)  Vtb   (bf16 V^T)
    //   [128M,160M) Obf   (bf16 attention out, [BT][1024])
    //   [160M,168M) Wt[4] (bf16 transposed weights)
    //   [168M,+64K) trig
    char* wsb = (char*)d_ws;
    const size_t MB32 = (size_t)32 << 20;
    __bf16* Abf = (__bf16*)(wsb);
    __bf16* Qbh = (__bf16*)(wsb + 1 * MB32);
    __bf16* Kbh = (__bf16*)(wsb + 2 * MB32);
    __bf16* Vtb = (__bf16*)(wsb + 3 * MB32);
    __bf16* Obf = (__bf16*)(wsb + 4 * MB32);
    __bf16* Wt  = (__bf16*)(wsb + 5 * MB32);
    __bf16* Wt0 = Wt;
    __bf16* Wt1 = Wt0 + (size_t)SZROW * SZROW;
    __bf16* Wt2 = Wt1 + (size_t)SZROW * SZROW;
    __bf16* Wt3 = Wt2 + (size_t)SZROW * SZROW;
    float2* trig = (float2*)(wsb + 5 * MB32 + 4 * ((size_t)SZROW * SZROW * 2));
    float* out = (float*)d_out;

    // RoPE table + neg-logit zero + all 4 weight transposes
    k_trig<<<32, 256, 0, stream>>>(trig);
    k_zero<<<BT / 256, 256, 0, stream>>>(out + (size_t)BT * SZROW);
    k_wt<<<dim3(32, 32, 4), 256, 0, stream>>>(Wq, Wk, Wv, Wo, Wt);

    // gather + cast activations
    k_cast<<<BT * 128 / 256, 256, 0, stream>>>(item_emb, log_seqs, Abf);

    // QKV projections with fused bias+RoPE+cast+relayout
    k_qkv<<<dim3(8, 128, 3), 256, 0, stream>>>(Abf, Wt0, Wt1, Wt2, bq, bk, bv,
                                               trig, Qbh, Kbh, Vtb);

    // MFMA flash attention -> Obf (bf16, [BT][1024])
    k_attn<<<dim3(8, 512), 256, 0, stream>>>(Qbh, Kbh, Vtb, Obf);

    // output projection fused with pos/neg logit epilogue
    k_projepi<<<dim3(8, 128), 256, 0, stream>>>(Obf, Wt3, bo, item_emb,
                                                pos_seqs, neg_seqs, out);
}